// Round 4
// baseline (463.212 us; speedup 1.0000x reference)
//
#include <hip/hip_runtime.h>
#include <cstddef>

#define H 128
#define W 192
#define KS 31
#define CF 64
#define NPIX (H*W)          // 24576
#define NKL (KS*KS)         // 961

// d_out layout (floats): out | pos | enorm | weights
#define OFF_POS (3*NPIX)            // 73728
#define OFF_EN  (OFF_POS + 2*NPIX)  // 122880
#define OFF_WGT (OFF_EN + NPIX)     // 147456

// workspace layout (floats)
#define NIMG NPIX
#define WS_CWT 0
#define WS_SWT 512
#define WS_CHT 1024
#define WS_SHT 1536
#define WS_U   2048
#define WS_V   (WS_U + 128*NIMG)
#define WS_Y   (WS_V + 128*NIMG)
#define WS_SN  (WS_Y + 128*NIMG)            // ushort[NPIX*64] viewed as floats
#define WS_TN  (WS_SN + 32*NIMG)            // NPIX*64 ushorts = 32*NIMG floats

#define PI_F 3.14159265358979323846f

typedef __attribute__((ext_vector_type(8))) short short8v;
typedef __attribute__((ext_vector_type(4))) float f32x4;

__device__ inline ushort bf16rtn(float f){
  uint u = __float_as_uint(f);
  u += 0x7fffu + ((u >> 16) & 1u);
  return (ushort)(u >> 16);
}

// ---------------- K1: filter tables (exact DFT sums, integer mod reduction) ---
__global__ __launch_bounds__(256) void k_tables(float* ws){
  int t = blockIdx.x*256 + threadIdx.x;
  if (t < 383){
    int d = t - 191;
    float c = 1.0f, s = 0.0f;
    for (int v = 1; v < 48; ++v){
      int m = (v*d) % 192; if (m < 0) m += 192;
      float a = (2.0f*PI_F/192.0f)*(float)m;
      c += 2.0f*cosf(a);
      s += 2.0f*sinf(a);
    }
    ws[WS_CWT + t] = c * (1.0f/192.0f);
    ws[WS_SWT + t] = s * (1.0f/192.0f);
  } else if (t < 383 + 255){
    int i = t - 383;
    int d = i - 127;
    float c = 0.0f, s = 0.0f;
    for (int u = 0; u < 32; ++u){
      int m = (u*d) % 128; if (m < 0) m += 128;
      float a = (2.0f*PI_F/128.0f)*(float)m;
      c += cosf(a);
      s += sinf(a);
    }
    ws[WS_CHT + i] = c * (1.0f/128.0f);
    ws[WS_SHT + i] = s * (1.0f/128.0f);
  }
}

// ---------------- K2: column pass  U = x*cwt, V = x*swt (tables in LDS) -------
__global__ __launch_bounds__(192) void k_colpass(const float* __restrict__ feats,
                                                const float* __restrict__ ws,
                                                float* __restrict__ U,
                                                float* __restrict__ V){
  __shared__ float xs[16][192];
  __shared__ float scw[384], ssw[384];
  int w  = threadIdx.x;
  int R0 = blockIdx.x * 16;
  for (int i = w; i < 383; i += 192){
    scw[i] = ws[WS_CWT + i];
    ssw[i] = ws[WS_SWT + i];
  }
#pragma unroll
  for (int r = 0; r < 16; ++r) xs[r][w] = feats[(size_t)(R0 + r)*192 + w];
  __syncthreads();
  float u[16], v[16];
#pragma unroll
  for (int r = 0; r < 16; ++r){ u[r] = 0.0f; v[r] = 0.0f; }
#pragma unroll 2
  for (int wp = 0; wp < 192; ++wp){
    float cw = scw[w - wp + 191];
    float sw = ssw[w - wp + 191];
#pragma unroll
    for (int r = 0; r < 16; ++r){
      float x = xs[r][wp];
      u[r] = fmaf(x, cw, u[r]);
      v[r] = fmaf(x, sw, v[r]);
    }
  }
#pragma unroll
  for (int r = 0; r < 16; ++r){
    U[(size_t)(R0 + r)*192 + w] = u[r];
    V[(size_t)(R0 + r)*192 + w] = v[r];
  }
}

// ---------------- K3: row pass  y = Ch*U - Sh*V -------------------------------
__global__ __launch_bounds__(192) void k_rowpass(const float* __restrict__ U,
                                                const float* __restrict__ V,
                                                const float* __restrict__ ws,
                                                float* __restrict__ Y){
  __shared__ float scht[255], ssht[255];
  int w = threadIdx.x;
  for (int i = w; i < 255; i += 192){
    scht[i] = ws[WS_CHT + i];
    ssht[i] = ws[WS_SHT + i];
  }
  __syncthreads();
  int ch = blockIdx.x >> 3;
  int h0 = (blockIdx.x & 7) * 16;
  const float* Uc = U + (size_t)ch*NIMG;
  const float* Vc = V + (size_t)ch*NIMG;
  float acc[16];
#pragma unroll
  for (int r = 0; r < 16; ++r) acc[r] = 0.0f;
  for (int hp = 0; hp < 128; ++hp){
    float uu = Uc[hp*192 + w];
    float vv = Vc[hp*192 + w];
#pragma unroll
    for (int r = 0; r < 16; ++r){
      int idx = h0 + r - hp + 127;
      acc[r] = fmaf(uu,  scht[idx], acc[r]);
      acc[r] = fmaf(-vv, ssht[idx], acc[r]);
    }
  }
  for (int r = 0; r < 16; ++r)
    Y[(size_t)ch*NIMG + (h0 + r)*192 + w] = acc[r];
}

// ---------------- K4: per-pixel channel normalization -> bf16 (h,w,c) ---------
__global__ __launch_bounds__(192) void k_norm(const float* __restrict__ Y,
                                              ushort* __restrict__ SNh,
                                              ushort* __restrict__ TNh){
  int h = blockIdx.x, w = threadIdx.x;
  int which = blockIdx.y;                // 0 = src, 1 = tgt
  int pix = h*192 + w;
  const float* base = Y + (size_t)which*64*NIMG + pix;
  float x[64];
  float ss = 0.0f;
#pragma unroll
  for (int c = 0; c < 64; ++c){
    x[c] = base[(size_t)c*NIMG];
    ss = fmaf(x[c], x[c], ss);
  }
  float rn = 1.0f / sqrtf(ss);
  ushort* o = (which ? TNh : SNh) + (size_t)pix*64;
#pragma unroll
  for (int q = 0; q < 8; ++q){
    ushort tmp[8];
#pragma unroll
    for (int e = 0; e < 8; ++e) tmp[e] = bf16rtn(x[q*8 + e] * rn);
    *reinterpret_cast<uint4*>(o + q*8) = *reinterpret_cast<const uint4*>(tmp);
  }
}

// ---------------- K5: fully fused corr + softmax + out/pos/enorm/weights ------
// Grid (128 h, 12 w-tiles), 64 threads (1 wave). |logit| <= temp (unit vectors)
// => fixed softmax offset exp(s - temp): no max pass, no rescaling.
// Two passes over k: pass1 accumulates sum/out/pos/enorm; pass2 recomputes
// scores (MFMA ~free) and writes normalized weights.
__global__ __launch_bounds__(64) void k_corrfused(const ushort* __restrict__ SNh,
                                                  const ushort* __restrict__ TNh,
                                                  const int* __restrict__ temp,
                                                  const float* __restrict__ frames,
                                                  float* __restrict__ dout){
  int h  = blockIdx.x;
  int bx = blockIdx.y;             // w-tile 0..11
  int lane = threadIdx.x;
  int n = lane & 15, g = lane >> 4;
  int w0 = bx * 16;
  float tempf = (float)(*temp);

  // A fragments: target row h, tile bx (held across both passes)
  const ushort* ap = TNh + ((size_t)(h*192 + w0 + n))*64 + g*8;
  short8v a0 = *reinterpret_cast<const short8v*>(ap);
  short8v a1 = *reinterpret_cast<const short8v*>(ap + 32);

  float sum[4] = {0,0,0,0};
  float ro0[4] = {0,0,0,0}, ro1[4] = {0,0,0,0}, ro2[4] = {0,0,0,0};
  float rp0[4] = {0,0,0,0}, rp1[4] = {0,0,0,0}, ren[4] = {0,0,0,0};

  // ---------------- pass 1 ----------------
  for (int k = 0; k < KS; ++k){
    int sh = h + k - 15; sh = sh < 0 ? 0 : (sh > 127 ? 127 : sh);
    float dy = (float)(k - 15);
    float dy2 = dy*dy;
    const ushort* srow = SNh + (size_t)sh*192*64;
#pragma unroll
    for (int dj = 0; dj < 3; ++dj){
      int j0 = bx - 1 + dj;
      if (j0 < 0 || j0 > 11) continue;
      const ushort* bp = srow + ((size_t)(j0*16 + n))*64 + g*8;
      short8v b0 = *reinterpret_cast<const short8v*>(bp);
      short8v b1 = *reinterpret_cast<const short8v*>(bp + 32);
      f32x4 acc = {0.0f, 0.0f, 0.0f, 0.0f};
      acc = __builtin_amdgcn_mfma_f32_16x16x32_bf16(a0, b0, acc, 0, 0, 0);
      acc = __builtin_amdgcn_mfma_f32_16x16x32_bf16(a1, b1, acc, 0, 0, 0);
      int sx = j0*16 + n;                  // 0..191 (valid tiles only)
      float f0 = frames[sh*192 + sx];
      float f1 = frames[NPIX   + sh*192 + sx];
      float f2 = frames[2*NPIX + sh*192 + sx];
#pragma unroll
      for (int r = 0; r < 4; ++r){
        int w = w0 + g*4 + r;
        int l = sx - w + 15;
        float e = __expf(acc[r]*tempf - tempf);
        if (l >= 0 && l <= 30){
          float dx = (float)(l - 15);
          sum[r] += e;
          ro0[r] = fmaf(e, f0, ro0[r]);
          ro1[r] = fmaf(e, f1, ro1[r]);
          ro2[r] = fmaf(e, f2, ro2[r]);
          rp0[r] = fmaf(e, dx, rp0[r]);
          rp1[r] = fmaf(e, dy, rp1[r]);
          ren[r] = fmaf(e, sqrtf(dx*dx + dy2), ren[r]);
        }
        if (bx == 0 && j0 == 0 && n == 0){          // left-edge replicas (sx<0 -> col 0)
          int cnt = 15 - w;
          if (cnt > 0){
            float fc = (float)cnt;
            sum[r] += fc*e;
            ro0[r] = fmaf(fc*e, f0, ro0[r]);
            ro1[r] = fmaf(fc*e, f1, ro1[r]);
            ro2[r] = fmaf(fc*e, f2, ro2[r]);
            rp1[r] = fmaf(fc*e, dy, rp1[r]);
            float sdx = 0.5f*(float)(w*(w+1)) - 120.0f;   // sum of dx over replicas
            rp0[r] = fmaf(e, sdx, rp0[r]);
            float se = 0.0f;
            for (int d = w + 1; d <= 15; ++d) se += sqrtf((float)(d*d) + dy2);
            ren[r] = fmaf(e, se, ren[r]);
          }
        }
        if (bx == 11 && j0 == 11 && n == 15){       // right-edge replicas (sx>191 -> col 191)
          int cnt = w - 176;
          if (cnt > 0){
            float fc = (float)cnt;
            sum[r] += fc*e;
            ro0[r] = fmaf(fc*e, f0, ro0[r]);
            ro1[r] = fmaf(fc*e, f1, ro1[r]);
            ro2[r] = fmaf(fc*e, f2, ro2[r]);
            rp1[r] = fmaf(fc*e, dy, rp1[r]);
            float sdx = 120.0f - 0.5f*(float)((191-w)*(192-w));
            rp0[r] = fmaf(e, sdx, rp0[r]);
            float se = 0.0f;
            for (int d = 192 - w; d <= 15; ++d) se += sqrtf((float)(d*d) + dy2);
            ren[r] = fmaf(e, se, ren[r]);
          }
        }
      }
    }
  }

  // reduce across the 16 lanes (n) of each g-group
#pragma unroll
  for (int mask = 1; mask <= 8; mask <<= 1){
#pragma unroll
    for (int r = 0; r < 4; ++r){
      sum[r] += __shfl_xor(sum[r], mask);
      ro0[r] += __shfl_xor(ro0[r], mask);
      ro1[r] += __shfl_xor(ro1[r], mask);
      ro2[r] += __shfl_xor(ro2[r], mask);
      rp0[r] += __shfl_xor(rp0[r], mask);
      rp1[r] += __shfl_xor(rp1[r], mask);
      ren[r] += __shfl_xor(ren[r], mask);
    }
  }
  float rs[4];
#pragma unroll
  for (int r = 0; r < 4; ++r) rs[r] = 1.0f / sum[r];

  if (n == 0){
#pragma unroll
    for (int r = 0; r < 4; ++r){
      int pix = h*192 + w0 + g*4 + r;
      dout[0*NPIX + pix] = ro0[r] * rs[r];
      dout[1*NPIX + pix] = ro1[r] * rs[r];
      dout[2*NPIX + pix] = ro2[r] * rs[r];
      dout[OFF_POS + pix*2 + 0] = rp0[r] * rs[r];
      dout[OFF_POS + pix*2 + 1] = rp1[r] * rs[r];
      dout[OFF_EN + pix] = ren[r] * rs[r];
    }
  }

  // ---------------- pass 2: write normalized weights ----------------
  float* wgt = dout + OFF_WGT;
  for (int k = 0; k < KS; ++k){
    int sh = h + k - 15; sh = sh < 0 ? 0 : (sh > 127 ? 127 : sh);
    const ushort* srow = SNh + (size_t)sh*192*64;
#pragma unroll
    for (int dj = 0; dj < 3; ++dj){
      int j0 = bx - 1 + dj;
      if (j0 < 0 || j0 > 11) continue;
      const ushort* bp = srow + ((size_t)(j0*16 + n))*64 + g*8;
      short8v b0 = *reinterpret_cast<const short8v*>(bp);
      short8v b1 = *reinterpret_cast<const short8v*>(bp + 32);
      f32x4 acc = {0.0f, 0.0f, 0.0f, 0.0f};
      acc = __builtin_amdgcn_mfma_f32_16x16x32_bf16(a0, b0, acc, 0, 0, 0);
      acc = __builtin_amdgcn_mfma_f32_16x16x32_bf16(a1, b1, acc, 0, 0, 0);
      int sx = j0*16 + n;
#pragma unroll
      for (int r = 0; r < 4; ++r){
        int w = w0 + g*4 + r;
        int l = sx - w + 15;
        float e = __expf(acc[r]*tempf - tempf) * rs[r];
        float* wp_ = wgt + (size_t)(h*192 + w)*NKL + k*KS;
        if (l >= 0 && l <= 30) wp_[l] = e;
        if (bx == 0 && j0 == 0 && n == 0){
          for (int l2 = 0; l2 < 15 - w; ++l2) wp_[l2] = e;
        }
        if (bx == 11 && j0 == 11 && n == 15){
          for (int l2 = 207 - w; l2 <= 30; ++l2) wp_[l2] = e;
        }
      }
    }
  }
}

extern "C" void kernel_launch(void* const* d_in, const int* in_sizes, int n_in,
                              void* d_out, int out_size, void* d_ws, size_t ws_size,
                              hipStream_t stream) {
  const float* frames = (const float*)d_in[0];   // (1,1,3,128,192)
  const float* feats  = (const float*)d_in[2];   // (1,2,64,128,192)
  const int*   temp   = (const int*)d_in[3];
  float* ws   = (float*)d_ws;
  float* dout = (float*)d_out;
  (void)in_sizes; (void)n_in; (void)out_size; (void)ws_size;

  float*  U   = ws + WS_U;
  float*  V   = ws + WS_V;
  float*  Y   = ws + WS_Y;
  ushort* SNh = (ushort*)(ws + WS_SN);
  ushort* TNh = (ushort*)(ws + WS_TN);

  hipLaunchKernelGGL(k_tables,    dim3(3),        dim3(256), 0, stream, ws);
  hipLaunchKernelGGL(k_colpass,   dim3(1024),     dim3(192), 0, stream, feats, ws, U, V);
  hipLaunchKernelGGL(k_rowpass,   dim3(1024),     dim3(192), 0, stream, U, V, ws, Y);
  hipLaunchKernelGGL(k_norm,      dim3(128, 2),   dim3(192), 0, stream, Y, SNh, TNh);
  hipLaunchKernelGGL(k_corrfused, dim3(128, 12),  dim3(64),  0, stream, SNh, TNh, temp, frames, dout);
}

// Round 5
// 338.272 us; speedup vs baseline: 1.3693x; 1.3693x over previous
//
#include <hip/hip_runtime.h>
#include <cstddef>

#define H 128
#define W 192
#define KS 31
#define CF 64
#define NPIX (H*W)          // 24576
#define NKL (KS*KS)         // 961

// d_out layout (floats): out | pos | enorm | weights
#define OFF_POS (3*NPIX)            // 73728
#define OFF_EN  (OFF_POS + 2*NPIX)  // 122880
#define OFF_WGT (OFF_EN + NPIX)     // 147456

// workspace layout (float offsets)
#define WS_CWH 0                    // 36864 ush = 18432 fl (Cw Toeplitz hi)
#define WS_CWL 18432
#define WS_SWH 36864
#define WS_SWL 55296
#define WS_CHH 73728                // 16384 ush = 8192 fl
#define WS_CHL 81920
#define WS_SHH 90112                // NEGATED Sh
#define WS_SHL 98304
#define WS_XH  131072               // 2359296 ush = 1179648 fl
#define WS_XL  (WS_XH + 1179648)    // ends 2490368
#define WS_UTH 2490368              // each plane 3145728 ush = 1572864 fl
#define WS_UTL (WS_UTH + 1572864)
#define WS_VTH (WS_UTL + 1572864)
#define WS_VTL (WS_VTH + 1572864)   // ends 8781824
#define WS_Y2  8781824              // 3145728 fl -> top 11927552 fl (47.7MB)
#define WS_SN2 131072               // reuse X region after filters done
#define WS_TN2 (WS_SN2 + 786432)

#define PI_F 3.14159265358979323846f

typedef __attribute__((ext_vector_type(8))) short short8v;
typedef __attribute__((ext_vector_type(4))) float f32x4;

__device__ inline ushort bf16rtn(float f){
  uint u = __float_as_uint(f);
  u += 0x7fffu + ((u >> 16) & 1u);
  return (ushort)(u >> 16);
}
__device__ inline float bf2f(ushort h){ return __uint_as_float((uint)h << 16); }
__device__ inline void bfsplit(float f, ushort& h, ushort& l){
  h = bf16rtn(f);
  l = bf16rtn(f - bf2f(h));
}

// ---------------- K1: Toeplitz DFT matrices, bf16 hi/lo (Sh negated) ----------
__global__ __launch_bounds__(256) void k_mats(float* ws){
  int e = blockIdx.x*256 + threadIdx.x;
  ushort* CWh = (ushort*)(ws + WS_CWH); ushort* CWl = (ushort*)(ws + WS_CWL);
  ushort* SWh = (ushort*)(ws + WS_SWH); ushort* SWl = (ushort*)(ws + WS_SWL);
  ushort* CHh = (ushort*)(ws + WS_CHH); ushort* CHl = (ushort*)(ws + WS_CHL);
  ushort* SHh = (ushort*)(ws + WS_SHH); ushort* SHl = (ushort*)(ws + WS_SHL);
  if (e < 36864){
    int w = e / 192, wp = e - w*192, d = w - wp;
    float c = 1.0f, s = 0.0f;
    for (int v = 1; v < 48; ++v){
      int m = (v*d) % 192; if (m < 0) m += 192;
      float a = (2.0f*PI_F/192.0f)*(float)m;
      c += 2.0f*cosf(a); s += 2.0f*sinf(a);
    }
    c *= (1.0f/192.0f); s *= (1.0f/192.0f);
    bfsplit(c, CWh[e], CWl[e]);
    bfsplit(s, SWh[e], SWl[e]);
  } else if (e < 36864 + 16384){
    int i = e - 36864;
    int h = i >> 7, hp = i & 127, d = h - hp;
    float c = 0.0f, s = 0.0f;
    for (int u = 0; u < 32; ++u){
      int m = (u*d) % 128; if (m < 0) m += 128;
      float a = (2.0f*PI_F/128.0f)*(float)m;
      c += cosf(a); s += sinf(a);
    }
    c *= (1.0f/128.0f); s *= (1.0f/128.0f);
    bfsplit(c,  CHh[i], CHl[i]);
    bfsplit(-s, SHh[i], SHl[i]);    // pre-negated for single-chain accumulate
  }
}

// ---------------- K2: split feats f32 -> bf16 hi/lo planes --------------------
__global__ __launch_bounds__(256) void k_split(const float* __restrict__ feats,
                                               ushort* __restrict__ Xh,
                                               ushort* __restrict__ Xl){
  int i = (blockIdx.x*256 + threadIdx.x)*8;     // 1152 blocks exact
  float4 v0 = *reinterpret_cast<const float4*>(feats + i);
  float4 v1 = *reinterpret_cast<const float4*>(feats + i + 4);
  ushort h[8], l[8];
  bfsplit(v0.x,h[0],l[0]); bfsplit(v0.y,h[1],l[1]); bfsplit(v0.z,h[2],l[2]); bfsplit(v0.w,h[3],l[3]);
  bfsplit(v1.x,h[4],l[4]); bfsplit(v1.y,h[5],l[5]); bfsplit(v1.z,h[6],l[6]); bfsplit(v1.w,h[7],l[7]);
  *reinterpret_cast<uint4*>(Xh + i) = *reinterpret_cast<const uint4*>(h);
  *reinterpret_cast<uint4*>(Xl + i) = *reinterpret_cast<const uint4*>(l);
}

// ---------------- K3: column pass via MFMA: U/V = X * {Cw,Sw}^T, transposed ---
// Grid (1024 row-tiles, 3), 4 waves; wave -> w-tile. Split-bf16 3-term MFMA.
__global__ __launch_bounds__(256) void k_colU(const ushort* __restrict__ Xh,
                                              const ushort* __restrict__ Xl,
                                              const float* __restrict__ ws,
                                              ushort* __restrict__ UTh, ushort* __restrict__ UTl,
                                              ushort* __restrict__ VTh, ushort* __restrict__ VTl){
  const ushort* CWh = (const ushort*)(ws + WS_CWH);
  const ushort* CWl = (const ushort*)(ws + WS_CWL);
  const ushort* SWh = (const ushort*)(ws + WS_SWH);
  const ushort* SWl = (const ushort*)(ws + WS_SWL);
  int R0 = blockIdx.x*16;
  int wv = threadIdx.x >> 6, lane = threadIdx.x & 63;
  int n = lane & 15, g = lane >> 4;
  int w0 = (blockIdx.y*4 + wv)*16;

  const ushort* xh = Xh + (size_t)(R0 + n)*192 + g*8;
  const ushort* xl = Xl + (size_t)(R0 + n)*192 + g*8;
  const ushort* cwh = CWh + (size_t)(w0 + n)*192 + g*8;
  const ushort* cwl = CWl + (size_t)(w0 + n)*192 + g*8;
  const ushort* swh = SWh + (size_t)(w0 + n)*192 + g*8;
  const ushort* swl = SWl + (size_t)(w0 + n)*192 + g*8;

  f32x4 aU = {0,0,0,0}, aV = {0,0,0,0};
#pragma unroll
  for (int ks = 0; ks < 6; ++ks){
    short8v ah = *reinterpret_cast<const short8v*>(xh + ks*32);
    short8v al = *reinterpret_cast<const short8v*>(xl + ks*32);
    short8v bh = *reinterpret_cast<const short8v*>(cwh + ks*32);
    short8v bl = *reinterpret_cast<const short8v*>(cwl + ks*32);
    aU = __builtin_amdgcn_mfma_f32_16x16x32_bf16(ah, bh, aU, 0, 0, 0);
    aU = __builtin_amdgcn_mfma_f32_16x16x32_bf16(ah, bl, aU, 0, 0, 0);
    aU = __builtin_amdgcn_mfma_f32_16x16x32_bf16(al, bh, aU, 0, 0, 0);
    short8v dh = *reinterpret_cast<const short8v*>(swh + ks*32);
    short8v dl = *reinterpret_cast<const short8v*>(swl + ks*32);
    aV = __builtin_amdgcn_mfma_f32_16x16x32_bf16(ah, dh, aV, 0, 0, 0);
    aV = __builtin_amdgcn_mfma_f32_16x16x32_bf16(ah, dl, aV, 0, 0, 0);
    aV = __builtin_amdgcn_mfma_f32_16x16x32_bf16(al, dh, aV, 0, 0, 0);
  }
  // store transposed hi/lo: UT[ch][w][hp]
  int ch = R0 >> 7, hp0 = R0 & 127;
  size_t base = ((size_t)(ch*192 + w0 + n))*128 + hp0 + g*4;
  ushort uh[4], ul[4], vh[4], vl[4];
#pragma unroll
  for (int r = 0; r < 4; ++r){
    bfsplit(aU[r], uh[r], ul[r]);
    bfsplit(aV[r], vh[r], vl[r]);
  }
  *reinterpret_cast<uint2*>(UTh + base) = *reinterpret_cast<const uint2*>(uh);
  *reinterpret_cast<uint2*>(UTl + base) = *reinterpret_cast<const uint2*>(ul);
  *reinterpret_cast<uint2*>(VTh + base) = *reinterpret_cast<const uint2*>(vh);
  *reinterpret_cast<uint2*>(VTl + base) = *reinterpret_cast<const uint2*>(vl);
}

// ---------------- K4: row pass via MFMA: Y = Ch*U + (-Sh)*V -------------------
// Grid (1024 = 128ch x 8 h-tiles, 3), 4 waves; wave -> w-tile.
__global__ __launch_bounds__(256) void k_rowY(const float* __restrict__ ws,
                                              const ushort* __restrict__ UTh, const ushort* __restrict__ UTl,
                                              const ushort* __restrict__ VTh, const ushort* __restrict__ VTl,
                                              float* __restrict__ Y){
  const ushort* CHh = (const ushort*)(ws + WS_CHH);
  const ushort* CHl = (const ushort*)(ws + WS_CHL);
  const ushort* SHh = (const ushort*)(ws + WS_SHH);
  const ushort* SHl = (const ushort*)(ws + WS_SHL);
  int ch = blockIdx.x >> 3;
  int h0 = (blockIdx.x & 7)*16;
  int wv = threadIdx.x >> 6, lane = threadIdx.x & 63;
  int n = lane & 15, g = lane >> 4;
  int w0 = (blockIdx.y*4 + wv)*16;

  const ushort* ahp = CHh + (size_t)(h0 + n)*128 + g*8;
  const ushort* alp = CHl + (size_t)(h0 + n)*128 + g*8;
  const ushort* shp = SHh + (size_t)(h0 + n)*128 + g*8;
  const ushort* slp = SHl + (size_t)(h0 + n)*128 + g*8;
  size_t brow = ((size_t)(ch*192 + w0 + n))*128 + g*8;

  f32x4 acc = {0,0,0,0};
#pragma unroll
  for (int ks = 0; ks < 4; ++ks){
    short8v ah = *reinterpret_cast<const short8v*>(ahp + ks*32);
    short8v al = *reinterpret_cast<const short8v*>(alp + ks*32);
    short8v uh = *reinterpret_cast<const short8v*>(UTh + brow + ks*32);
    short8v ul = *reinterpret_cast<const short8v*>(UTl + brow + ks*32);
    acc = __builtin_amdgcn_mfma_f32_16x16x32_bf16(ah, uh, acc, 0, 0, 0);
    acc = __builtin_amdgcn_mfma_f32_16x16x32_bf16(ah, ul, acc, 0, 0, 0);
    acc = __builtin_amdgcn_mfma_f32_16x16x32_bf16(al, uh, acc, 0, 0, 0);
    short8v sh = *reinterpret_cast<const short8v*>(shp + ks*32);
    short8v sl = *reinterpret_cast<const short8v*>(slp + ks*32);
    short8v vh = *reinterpret_cast<const short8v*>(VTh + brow + ks*32);
    short8v vl = *reinterpret_cast<const short8v*>(VTl + brow + ks*32);
    acc = __builtin_amdgcn_mfma_f32_16x16x32_bf16(sh, vh, acc, 0, 0, 0);
    acc = __builtin_amdgcn_mfma_f32_16x16x32_bf16(sh, vl, acc, 0, 0, 0);
    acc = __builtin_amdgcn_mfma_f32_16x16x32_bf16(sl, vh, acc, 0, 0, 0);
  }
#pragma unroll
  for (int r = 0; r < 4; ++r)
    Y[(size_t)(ch*128 + h0 + g*4 + r)*192 + w0 + n] = acc[r];
}

// ---------------- K5: per-pixel channel normalization -> bf16 (h,w,c) ---------
__global__ __launch_bounds__(192) void k_norm(const float* __restrict__ Y,
                                              ushort* __restrict__ SNh,
                                              ushort* __restrict__ TNh){
  int h = blockIdx.x, w = threadIdx.x;
  int which = blockIdx.y;                // 0 = src, 1 = tgt
  int pix = h*192 + w;
  const float* base = Y + (size_t)which*64*NPIX + pix;
  float x[64];
  float ss = 0.0f;
#pragma unroll
  for (int c = 0; c < 64; ++c){
    x[c] = base[(size_t)c*NPIX];
    ss = fmaf(x[c], x[c], ss);
  }
  float rn = 1.0f / sqrtf(ss);
  ushort* o = (which ? TNh : SNh) + (size_t)pix*64;
#pragma unroll
  for (int q = 0; q < 8; ++q){
    ushort tmp[8];
#pragma unroll
    for (int e = 0; e < 8; ++e) tmp[e] = bf16rtn(x[q*8 + e] * rn);
    *reinterpret_cast<uint4*>(o + q*8) = *reinterpret_cast<const uint4*>(tmp);
  }
}

// ---------------- K6: banded-GEMM correlation via MFMA (round-3 proven) -------
__global__ __launch_bounds__(256) void k_corr(const ushort* __restrict__ SNh,
                                              const ushort* __restrict__ TNh,
                                              const int* __restrict__ temp,
                                              float* __restrict__ wgt){
  int h = blockIdx.x, k = blockIdx.y;
  int lane = threadIdx.x & 63;
  int wv = threadIdx.x >> 6;
  int i0base = wv * 3;
  int n = lane & 15, g = lane >> 4;
  float tempf = (float)(*temp);
  int sh = h + k - 15; sh = sh < 0 ? 0 : (sh > 127 ? 127 : sh);

  short8v a[3][2];
#pragma unroll
  for (int i = 0; i < 3; ++i){
    const ushort* p = TNh + ((size_t)(h*192 + (i0base + i)*16 + n))*64 + g*8;
#pragma unroll
    for (int ks = 0; ks < 2; ++ks)
      a[i][ks] = *reinterpret_cast<const short8v*>(p + ks*32);
  }
  short8v b[5][2];
  int j0lo = i0base - 1;
#pragma unroll
  for (int j = 0; j < 5; ++j){
    int j0 = j0lo + j;
    if (j0 < 0 || j0 > 11) continue;
    const ushort* p = SNh + ((size_t)(sh*192 + j0*16 + n))*64 + g*8;
#pragma unroll
    for (int ks = 0; ks < 2; ++ks)
      b[j][ks] = *reinterpret_cast<const short8v*>(p + ks*32);
  }

  float* base = wgt + ((size_t)(h*192))*NKL + (size_t)k*KS;
#pragma unroll
  for (int i = 0; i < 3; ++i){
    int i0 = i0base + i;
#pragma unroll
    for (int dj = -1; dj <= 1; ++dj){
      int j0 = i0 + dj;
      if (j0 < 0 || j0 > 11) continue;
      int jj = i + dj + 1;
      f32x4 acc = {0.0f, 0.0f, 0.0f, 0.0f};
      acc = __builtin_amdgcn_mfma_f32_16x16x32_bf16(a[i][0], b[jj][0], acc, 0, 0, 0);
      acc = __builtin_amdgcn_mfma_f32_16x16x32_bf16(a[i][1], b[jj][1], acc, 0, 0, 0);
      int sx = j0*16 + n;
#pragma unroll
      for (int r = 0; r < 4; ++r){
        int m = g*4 + r;
        int w = i0*16 + m;
        int l = sx - w + 15;
        float v = acc[r] * tempf;
        if (l >= 0 && l <= 30) base[(size_t)w*NKL + l] = v;
        if (j0 == 0 && n == 0){
          for (int l2 = 0; l2 < 15 - w; ++l2) base[(size_t)w*NKL + l2] = v;
        }
        if (j0 == 11 && n == 15){
          for (int l2 = 207 - w; l2 <= 30; ++l2) base[(size_t)w*NKL + l2] = v;
        }
      }
    }
  }
}

// ---------------- K7: fused softmax + weights + out/pos/enorm -----------------
__global__ __launch_bounds__(256) void k_fused(float* __restrict__ dout,
                                               const float* __restrict__ frames){
  __shared__ float red[256];
  __shared__ float red6[6][256];
  int pix = blockIdx.x, t = threadIdx.x;
  int h = pix / 192, w = pix % 192;
  float* wp_ = dout + OFF_WGT + (size_t)pix*NKL;

  float x[4];
#pragma unroll
  for (int j = 0; j < 4; ++j){
    int i = t + 256*j;
    x[j] = (i < NKL) ? wp_[i] : -3.4e38f;
  }
  float m = fmaxf(fmaxf(x[0], x[1]), fmaxf(x[2], x[3]));
  red[t] = m; __syncthreads();
  for (int s = 128; s > 0; s >>= 1){
    if (t < s) red[t] = fmaxf(red[t], red[t + s]);
    __syncthreads();
  }
  float mall = red[0]; __syncthreads();

  float e[4];
  float sum = 0.0f;
#pragma unroll
  for (int j = 0; j < 4; ++j){
    int i = t + 256*j;
    e[j] = (i < NKL) ? expf(x[j] - mall) : 0.0f;
    sum += e[j];
  }
  red[t] = sum; __syncthreads();
  for (int s = 128; s > 0; s >>= 1){
    if (t < s) red[t] += red[t + s];
    __syncthreads();
  }
  float rs = 1.0f / red[0];

  float o0=0, o1=0, o2=0, p0=0, p1=0, en=0;
#pragma unroll
  for (int j = 0; j < 4; ++j){
    int i = t + 256*j;
    if (i < NKL){
      int k = i / 31, l = i - k*31;
      float ev = e[j] * rs;
      wp_[i] = ev;
      float dy = (float)(k - 15), dx = (float)(l - 15);
      p0 = fmaf(ev, dx, p0);
      p1 = fmaf(ev, dy, p1);
      en = fmaf(ev, sqrtf(dx*dx + dy*dy), en);
      int hh = h + k - 15; hh = hh < 0 ? 0 : (hh > 127 ? 127 : hh);
      int ww = w + l - 15; ww = ww < 0 ? 0 : (ww > 191 ? 191 : ww);
      const float* f = frames + hh*192 + ww;
      o0 = fmaf(ev, f[0],      o0);
      o1 = fmaf(ev, f[NPIX],   o1);
      o2 = fmaf(ev, f[2*NPIX], o2);
    }
  }
  red6[0][t]=o0; red6[1][t]=o1; red6[2][t]=o2; red6[3][t]=p0; red6[4][t]=p1; red6[5][t]=en;
  __syncthreads();
  for (int s = 128; s > 0; s >>= 1){
    if (t < s){
#pragma unroll
      for (int q = 0; q < 6; ++q) red6[q][t] += red6[q][t + s];
    }
    __syncthreads();
  }
  if (t == 0){
    dout[0*NPIX + pix] = red6[0][0];
    dout[1*NPIX + pix] = red6[1][0];
    dout[2*NPIX + pix] = red6[2][0];
    dout[OFF_POS + pix*2 + 0] = red6[3][0];
    dout[OFF_POS + pix*2 + 1] = red6[4][0];
    dout[OFF_EN + pix] = red6[5][0];
  }
}

extern "C" void kernel_launch(void* const* d_in, const int* in_sizes, int n_in,
                              void* d_out, int out_size, void* d_ws, size_t ws_size,
                              hipStream_t stream) {
  const float* frames = (const float*)d_in[0];   // (1,1,3,128,192)
  const float* feats  = (const float*)d_in[2];   // (1,2,64,128,192)
  const int*   temp   = (const int*)d_in[3];
  float* ws   = (float*)d_ws;
  float* dout = (float*)d_out;
  (void)in_sizes; (void)n_in; (void)out_size; (void)ws_size;

  ushort* Xh  = (ushort*)(ws + WS_XH);
  ushort* Xl  = (ushort*)(ws + WS_XL);
  ushort* UTh = (ushort*)(ws + WS_UTH);
  ushort* UTl = (ushort*)(ws + WS_UTL);
  ushort* VTh = (ushort*)(ws + WS_VTH);
  ushort* VTl = (ushort*)(ws + WS_VTL);
  float*  Y   = ws + WS_Y2;
  ushort* SNh = (ushort*)(ws + WS_SN2);
  ushort* TNh = (ushort*)(ws + WS_TN2);

  hipLaunchKernelGGL(k_mats,   dim3(208),      dim3(256), 0, stream, ws);
  hipLaunchKernelGGL(k_split,  dim3(1152),     dim3(256), 0, stream, feats, Xh, Xl);
  hipLaunchKernelGGL(k_colU,   dim3(1024, 3),  dim3(256), 0, stream, Xh, Xl, ws, UTh, UTl, VTh, VTl);
  hipLaunchKernelGGL(k_rowY,   dim3(1024, 3),  dim3(256), 0, stream, ws, UTh, UTl, VTh, VTl, Y);
  hipLaunchKernelGGL(k_norm,   dim3(128, 2),   dim3(192), 0, stream, Y, SNh, TNh);
  hipLaunchKernelGGL(k_corr,   dim3(128, 31),  dim3(256), 0, stream, SNh, TNh, temp, dout + OFF_WGT);
  hipLaunchKernelGGL(k_fused,  dim3(NPIX),     dim3(256), 0, stream, dout, frames);
}

// Round 6
// 326.454 us; speedup vs baseline: 1.4189x; 1.0362x over previous
//
#include <hip/hip_runtime.h>
#include <cstddef>

#define H 128
#define W 192
#define KS 31
#define CF 64
#define NPIX (H*W)          // 24576
#define NKL (KS*KS)         // 961

// d_out layout (floats): out | pos | enorm | weights
#define OFF_POS (3*NPIX)            // 73728
#define OFF_EN  (OFF_POS + 2*NPIX)  // 122880
#define OFF_WGT (OFF_EN + NPIX)     // 147456

// workspace layout (floats)
#define NIMG NPIX
#define WS_CWT 0
#define WS_SWT 512
#define WS_CHT 1024
#define WS_SHT 1536
#define WS_U   2048
#define WS_V   (WS_U + 128*NIMG)
#define WS_Y   (WS_V + 128*NIMG)
#define WS_SN  (WS_Y + 128*NIMG)            // ushort[NPIX*64] viewed as floats
#define WS_TN  (WS_SN + 32*NIMG)            // NPIX*64 ushorts = 32*NIMG floats

#define PI_F 3.14159265358979323846f

typedef __attribute__((ext_vector_type(8))) short short8v;
typedef __attribute__((ext_vector_type(4))) float f32x4;

__device__ inline ushort bf16rtn(float f){
  uint u = __float_as_uint(f);
  u += 0x7fffu + ((u >> 16) & 1u);
  return (ushort)(u >> 16);
}

// ---------------- K1: filter tables (exact DFT sums, integer mod reduction) ---
__global__ __launch_bounds__(256) void k_tables(float* ws){
  int t = blockIdx.x*256 + threadIdx.x;
  if (t < 383){
    int d = t - 191;
    float c = 1.0f, s = 0.0f;
    for (int v = 1; v < 48; ++v){
      int m = (v*d) % 192; if (m < 0) m += 192;
      float a = (2.0f*PI_F/192.0f)*(float)m;
      c += 2.0f*cosf(a);
      s += 2.0f*sinf(a);
    }
    ws[WS_CWT + t] = c * (1.0f/192.0f);
    ws[WS_SWT + t] = s * (1.0f/192.0f);
  } else if (t < 383 + 255){
    int i = t - 383;
    int d = i - 127;
    float c = 0.0f, s = 0.0f;
    for (int u = 0; u < 32; ++u){
      int m = (u*d) % 128; if (m < 0) m += 128;
      float a = (2.0f*PI_F/128.0f)*(float)m;
      c += cosf(a);
      s += sinf(a);
    }
    ws[WS_CHT + i] = c * (1.0f/128.0f);
    ws[WS_SHT + i] = s * (1.0f/128.0f);
  }
}

// ---------------- K2: column pass  U = x*cwt, V = x*swt (f32, tables in LDS) --
__global__ __launch_bounds__(192) void k_colpass(const float* __restrict__ feats,
                                                const float* __restrict__ ws,
                                                float* __restrict__ U,
                                                float* __restrict__ V){
  __shared__ float xs[16][192];
  __shared__ float scw[384], ssw[384];
  int w  = threadIdx.x;
  int R0 = blockIdx.x * 16;
  for (int i = w; i < 383; i += 192){
    scw[i] = ws[WS_CWT + i];
    ssw[i] = ws[WS_SWT + i];
  }
#pragma unroll
  for (int r = 0; r < 16; ++r) xs[r][w] = feats[(size_t)(R0 + r)*192 + w];
  __syncthreads();
  float u[16], v[16];
#pragma unroll
  for (int r = 0; r < 16; ++r){ u[r] = 0.0f; v[r] = 0.0f; }
#pragma unroll 2
  for (int wp = 0; wp < 192; ++wp){
    float cw = scw[w - wp + 191];
    float sw = ssw[w - wp + 191];
#pragma unroll
    for (int r = 0; r < 16; ++r){
      float x = xs[r][wp];
      u[r] = fmaf(x, cw, u[r]);
      v[r] = fmaf(x, sw, v[r]);
    }
  }
#pragma unroll
  for (int r = 0; r < 16; ++r){
    U[(size_t)(R0 + r)*192 + w] = u[r];
    V[(size_t)(R0 + r)*192 + w] = v[r];
  }
}

// ---------------- K3: row pass  y = Ch*U - Sh*V (f32) -------------------------
__global__ __launch_bounds__(192) void k_rowpass(const float* __restrict__ U,
                                                const float* __restrict__ V,
                                                const float* __restrict__ ws,
                                                float* __restrict__ Y){
  __shared__ float scht[255], ssht[255];
  int w = threadIdx.x;
  for (int i = w; i < 255; i += 192){
    scht[i] = ws[WS_CHT + i];
    ssht[i] = ws[WS_SHT + i];
  }
  __syncthreads();
  int ch = blockIdx.x >> 3;
  int h0 = (blockIdx.x & 7) * 16;
  const float* Uc = U + (size_t)ch*NIMG;
  const float* Vc = V + (size_t)ch*NIMG;
  float acc[16];
#pragma unroll
  for (int r = 0; r < 16; ++r) acc[r] = 0.0f;
  for (int hp = 0; hp < 128; ++hp){
    float uu = Uc[hp*192 + w];
    float vv = Vc[hp*192 + w];
#pragma unroll
    for (int r = 0; r < 16; ++r){
      int idx = h0 + r - hp + 127;
      acc[r] = fmaf(uu,  scht[idx], acc[r]);
      acc[r] = fmaf(-vv, ssht[idx], acc[r]);
    }
  }
  for (int r = 0; r < 16; ++r)
    Y[(size_t)ch*NIMG + (h0 + r)*192 + w] = acc[r];
}

// ---------------- K4: per-pixel channel normalization -> bf16 (h,w,c) ---------
__global__ __launch_bounds__(192) void k_norm(const float* __restrict__ Y,
                                              ushort* __restrict__ SNh,
                                              ushort* __restrict__ TNh){
  int h = blockIdx.x, w = threadIdx.x;
  int which = blockIdx.y;                // 0 = src, 1 = tgt
  int pix = h*192 + w;
  const float* base = Y + (size_t)which*64*NIMG + pix;
  float x[64];
  float ss = 0.0f;
#pragma unroll
  for (int c = 0; c < 64; ++c){
    x[c] = base[(size_t)c*NIMG];
    ss = fmaf(x[c], x[c], ss);
  }
  float rn = 1.0f / sqrtf(ss);
  ushort* o = (which ? TNh : SNh) + (size_t)pix*64;
#pragma unroll
  for (int q = 0; q < 8; ++q){
    ushort tmp[8];
#pragma unroll
    for (int e = 0; e < 8; ++e) tmp[e] = bf16rtn(x[q*8 + e] * rn);
    *reinterpret_cast<uint4*>(o + q*8) = *reinterpret_cast<const uint4*>(tmp);
  }
}

// ---------------- K5: fused corr + softmax + outputs, LDS e-cache -------------
// Block = (h, 16-w tile), 4 waves. |logit| <= temp (unit vectors) => fixed
// offset exp(s-temp), no max pass. Waves split k; e staged in LDS; block
// reduces sum/out/pos/enorm; weights written once, coalesced.
__global__ __launch_bounds__(256) void k_corrsm(const ushort* __restrict__ SNh,
                                                const ushort* __restrict__ TNh,
                                                const int* __restrict__ temp,
                                                const float* __restrict__ frames,
                                                float* __restrict__ dout){
  __shared__ float eL[16][993];          // stride 993 % 32 == 1: conflict-free
  __shared__ float red7[7][16][16];
  __shared__ float rsw[16];
  int h  = blockIdx.x;
  int bx = blockIdx.y;                   // w-tile 0..11
  int t  = threadIdx.x;
  int lane = t & 63, wv = t >> 6;
  int n = lane & 15, g = lane >> 4;
  int w0 = bx * 16;
  float tempf = (float)(*temp);

  // A fragments: target row h, tile bx
  const ushort* ap = TNh + ((size_t)(h*192 + w0 + n))*64 + g*8;
  short8v a0 = *reinterpret_cast<const short8v*>(ap);
  short8v a1 = *reinterpret_cast<const short8v*>(ap + 32);

  // ---- fill pass: waves split k ----
  for (int k = wv; k < KS; k += 4){
    int sh = h + k - 15; sh = sh < 0 ? 0 : (sh > 127 ? 127 : sh);
    const ushort* srow = SNh + (size_t)sh*192*64;
#pragma unroll
    for (int dj = 0; dj < 3; ++dj){
      int j0 = bx - 1 + dj;
      if (j0 < 0 || j0 > 11) continue;
      const ushort* bp = srow + ((size_t)(j0*16 + n))*64 + g*8;
      short8v b0 = *reinterpret_cast<const short8v*>(bp);
      short8v b1 = *reinterpret_cast<const short8v*>(bp + 32);
      f32x4 acc = {0.0f, 0.0f, 0.0f, 0.0f};
      acc = __builtin_amdgcn_mfma_f32_16x16x32_bf16(a0, b0, acc, 0, 0, 0);
      acc = __builtin_amdgcn_mfma_f32_16x16x32_bf16(a1, b1, acc, 0, 0, 0);
      int sx = j0*16 + n;
#pragma unroll
      for (int r = 0; r < 4; ++r){
        int wl = g*4 + r;
        int wg = w0 + wl;
        int l = sx - wg + 15;
        float e = __expf(acc[r]*tempf - tempf);
        if (l >= 0 && l <= 30) eL[wl][k*31 + l] = e;
        if (bx == 0 && j0 == 0 && n == 0){          // left edge: sx<0 -> col 0
          for (int l2 = 0; l2 < 15 - wg; ++l2) eL[wl][k*31 + l2] = e;
        }
        if (bx == 11 && j0 == 11 && n == 15){       // right edge: sx>191 -> col 191
          for (int l2 = 207 - wg; l2 <= 30; ++l2) eL[wl][k*31 + l2] = e;
        }
      }
    }
  }
  __syncthreads();

  // ---- reduction pass: thread t -> w = t&15, k in {t>>4, t>>4 + 16} ----
  {
    float s=0, o0=0, o1=0, o2=0, p0=0, p1=0, en=0;
    int wl = t & 15;
    int wg = w0 + wl;
    for (int kk = t >> 4; kk < KS; kk += 16){
      int sh = h + kk - 15; sh = sh < 0 ? 0 : (sh > 127 ? 127 : sh);
      float dy = (float)(kk - 15);
      float dy2 = dy*dy;
      const float* f0p = frames + sh*192;
      const float* f1p = f0p + NPIX;
      const float* f2p = f0p + 2*NPIX;
      const float* src = eL[wl] + kk*31;
#pragma unroll
      for (int l = 0; l < KS; ++l){
        float e = src[l];
        float dx = (float)(l - 15);
        int ww = wg + l - 15; ww = ww < 0 ? 0 : (ww > 191 ? 191 : ww);
        s  += e;
        p0 = fmaf(e, dx, p0);
        p1 = fmaf(e, dy, p1);
        en = fmaf(e, sqrtf(dx*dx + dy2), en);
        o0 = fmaf(e, f0p[ww], o0);
        o1 = fmaf(e, f1p[ww], o1);
        o2 = fmaf(e, f2p[ww], o2);
      }
    }
    int q = t >> 4;
    red7[0][q][wl]=s;  red7[1][q][wl]=o0; red7[2][q][wl]=o1; red7[3][q][wl]=o2;
    red7[4][q][wl]=p0; red7[5][q][wl]=p1; red7[6][q][wl]=en;
  }
  __syncthreads();

  if (t < 16){
    float a[7];
#pragma unroll
    for (int j = 0; j < 7; ++j){
      float acc = 0.0f;
#pragma unroll
      for (int qq = 0; qq < 16; ++qq) acc += red7[j][qq][t];
      a[j] = acc;
    }
    float rs = 1.0f / a[0];
    int pix = h*192 + w0 + t;
    dout[0*NPIX + pix] = a[1]*rs;
    dout[1*NPIX + pix] = a[2]*rs;
    dout[2*NPIX + pix] = a[3]*rs;
    dout[OFF_POS + pix*2 + 0] = a[4]*rs;
    dout[OFF_POS + pix*2 + 1] = a[5]*rs;
    dout[OFF_EN + pix] = a[6]*rs;
    rsw[t] = rs;
  }
  __syncthreads();

  // ---- write pass: 16 consecutive threads stream one 961-row (coalesced) ----
  {
    int w2 = t >> 4, q2 = t & 15;
    float rs = rsw[w2];
    float* dst = dout + OFF_WGT + ((size_t)(h*192 + w0 + w2))*NKL;
    const float* src = eL[w2];
    for (int j = q2; j < NKL; j += 16)
      dst[j] = src[j] * rs;
  }
}

extern "C" void kernel_launch(void* const* d_in, const int* in_sizes, int n_in,
                              void* d_out, int out_size, void* d_ws, size_t ws_size,
                              hipStream_t stream) {
  const float* frames = (const float*)d_in[0];   // (1,1,3,128,192)
  const float* feats  = (const float*)d_in[2];   // (1,2,64,128,192)
  const int*   temp   = (const int*)d_in[3];
  float* ws   = (float*)d_ws;
  float* dout = (float*)d_out;
  (void)in_sizes; (void)n_in; (void)out_size; (void)ws_size;

  float*  U   = ws + WS_U;
  float*  V   = ws + WS_V;
  float*  Y   = ws + WS_Y;
  ushort* SNh = (ushort*)(ws + WS_SN);
  ushort* TNh = (ushort*)(ws + WS_TN);

  hipLaunchKernelGGL(k_tables,  dim3(3),        dim3(256), 0, stream, ws);
  hipLaunchKernelGGL(k_colpass, dim3(1024),     dim3(192), 0, stream, feats, ws, U, V);
  hipLaunchKernelGGL(k_rowpass, dim3(1024),     dim3(192), 0, stream, U, V, ws, Y);
  hipLaunchKernelGGL(k_norm,    dim3(128, 2),   dim3(192), 0, stream, Y, SNh, TNh);
  hipLaunchKernelGGL(k_corrsm,  dim3(128, 12),  dim3(256), 0, stream, SNh, TNh, temp, frames, dout);
}

// Round 7
// 307.289 us; speedup vs baseline: 1.5074x; 1.0624x over previous
//
#include <hip/hip_runtime.h>
#include <cstddef>

#define H 128
#define W 192
#define KS 31
#define CF 64
#define NPIX (H*W)          // 24576
#define NKL (KS*KS)         // 961

// d_out layout (floats): out | pos | enorm | weights
#define OFF_POS (3*NPIX)            // 73728
#define OFF_EN  (OFF_POS + 2*NPIX)  // 122880
#define OFF_WGT (OFF_EN + NPIX)     // 147456

// workspace layout (floats)
#define NIMG NPIX
#define WS_CWT 0
#define WS_SWT 512
#define WS_CHT 1024
#define WS_SHT 1536
#define WS_U   2048                          // UV interleaved: 2*128*NIMG floats
#define WS_Y   (WS_U + 2*128*NIMG)
#define WS_SN  (WS_Y + 128*NIMG)            // ushort[NPIX*64] viewed as floats
#define WS_TN  (WS_SN + 32*NIMG)

#define PI_F 3.14159265358979323846f
#define ELS 962                              // eL row stride (ushorts); 962%64==2

typedef __attribute__((ext_vector_type(8))) short short8v;
typedef __attribute__((ext_vector_type(4))) float f32x4;

__device__ inline ushort bf16rtn(float f){
  uint u = __float_as_uint(f);
  u += 0x7fffu + ((u >> 16) & 1u);
  return (ushort)(u >> 16);
}
__device__ inline float bf2f(ushort h){ return __uint_as_float((uint)h << 16); }

// ---------------- K1: filter tables (exact DFT sums, integer mod reduction) ---
__global__ __launch_bounds__(256) void k_tables(float* ws){
  int t = blockIdx.x*256 + threadIdx.x;
  if (t < 383){
    int d = t - 191;
    float c = 1.0f, s = 0.0f;
    for (int v = 1; v < 48; ++v){
      int m = (v*d) % 192; if (m < 0) m += 192;
      float a = (2.0f*PI_F/192.0f)*(float)m;
      c += 2.0f*cosf(a);
      s += 2.0f*sinf(a);
    }
    ws[WS_CWT + t] = c * (1.0f/192.0f);
    ws[WS_SWT + t] = s * (1.0f/192.0f);
  } else if (t < 383 + 255){
    int i = t - 383;
    int d = i - 127;
    float c = 0.0f, s = 0.0f;
    for (int u = 0; u < 32; ++u){
      int m = (u*d) % 128; if (m < 0) m += 128;
      float a = (2.0f*PI_F/128.0f)*(float)m;
      c += cosf(a);
      s += sinf(a);
    }
    ws[WS_CHT + i] = c * (1.0f/128.0f);
    ws[WS_SHT + i] = s * (1.0f/128.0f);
  }
}

// ---------------- K2: column pass  UV = x * {cwt,swt}, float2 out -------------
// Per 4-wp: 2 b128 table reads (4 shifted copies, phase = w&3) + 16 float4
// broadcasts of x + 128 FMA.  VALU-bound.
__global__ __launch_bounds__(192) void k_colpass(const float* __restrict__ feats,
                                                const float* __restrict__ ws,
                                                float2* __restrict__ UV2){
  __shared__ float xs[16][192];
  __shared__ float tc[4][392], tn[4][392];
  int w  = threadIdx.x;
  int R0 = blockIdx.x * 16;
  for (int i = w; i < 380; i += 192){
#pragma unroll
    for (int s = 0; s < 4; ++s){
      tc[s][i] = ws[WS_CWT + i + s];     // i+s <= 382, table len 383
      tn[s][i] = ws[WS_SWT + i + s];
    }
  }
#pragma unroll
  for (int r = 0; r < 16; ++r) xs[r][w] = feats[(size_t)(R0 + r)*192 + w];
  __syncthreads();

  const int s = w & 3;
  const int boff = (w & ~3) + 188;           // (w - s) + 188, %4 == 0
  const float* tcs = tc[s];
  const float* tns = tn[s];

  float u[16], v[16];
#pragma unroll
  for (int r = 0; r < 16; ++r){ u[r] = 0.0f; v[r] = 0.0f; }

  for (int wp0 = 0; wp0 < 192; wp0 += 4){
    const float4 cw4 = *reinterpret_cast<const float4*>(tcs + (boff - wp0));
    const float4 sw4 = *reinterpret_cast<const float4*>(tns + (boff - wp0));
    // c(wp0+j) = cw4[3-j]
#pragma unroll
    for (int r = 0; r < 16; ++r){
      const float4 x4 = *reinterpret_cast<const float4*>(&xs[r][wp0]);
      u[r] = fmaf(x4.x, cw4.w, u[r]);
      u[r] = fmaf(x4.y, cw4.z, u[r]);
      u[r] = fmaf(x4.z, cw4.y, u[r]);
      u[r] = fmaf(x4.w, cw4.x, u[r]);
      v[r] = fmaf(x4.x, sw4.w, v[r]);
      v[r] = fmaf(x4.y, sw4.z, v[r]);
      v[r] = fmaf(x4.z, sw4.y, v[r]);
      v[r] = fmaf(x4.w, sw4.x, v[r]);
    }
  }
#pragma unroll
  for (int r = 0; r < 16; ++r)
    UV2[(size_t)(R0 + r)*192 + w] = make_float2(u[r], v[r]);
}

// ---------------- K3: row pass  y = Ch*U + (-Sh)*V ----------------------------
// Tables: per-block 143-value window, 4 shifted copies, uniform b128 broadcasts.
__global__ __launch_bounds__(192) void k_rowpass(const float2* __restrict__ UV2,
                                                const float* __restrict__ ws,
                                                float* __restrict__ Y){
  __shared__ float Lc[4][144], Ls[4][144];
  int w = threadIdx.x;
  int ch = blockIdx.x >> 3;
  int h0 = (blockIdx.x & 7) * 16;
  for (int i = w; i < 143; i += 192){
#pragma unroll
    for (int s = 0; s < 4; ++s){
      int gi = h0 + i + s;
      Lc[s][i] = (gi < 255) ?  ws[WS_CHT + gi] : 0.0f;
      Ls[s][i] = (gi < 255) ? -ws[WS_SHT + gi] : 0.0f;   // negated
    }
  }
  __syncthreads();
  const float2* Uc = UV2 + (size_t)ch*NIMG;

  float acc[16];
#pragma unroll
  for (int r = 0; r < 16; ++r) acc[r] = 0.0f;

  for (int hp0 = 0; hp0 < 128; hp0 += 4){
    float2 uv0 = Uc[(hp0+0)*192 + w];
    float2 uv1 = Uc[(hp0+1)*192 + w];
    float2 uv2 = Uc[(hp0+2)*192 + w];
    float2 uv3 = Uc[(hp0+3)*192 + w];
#pragma unroll
    for (int r = 0; r < 16; ++r){
      int lb = 124 + (r & ~3) - hp0;          // (124 + r - hp0) - (r&3), %4==0
      const float4 c4 = *reinterpret_cast<const float4*>(&Lc[r & 3][lb]);
      const float4 s4 = *reinterpret_cast<const float4*>(&Ls[r & 3][lb]);
      // cht(h0+r-hp0-j+127) = c4[3-j]
      acc[r] = fmaf(uv0.x, c4.w, acc[r]);
      acc[r] = fmaf(uv0.y, s4.w, acc[r]);
      acc[r] = fmaf(uv1.x, c4.z, acc[r]);
      acc[r] = fmaf(uv1.y, s4.z, acc[r]);
      acc[r] = fmaf(uv2.x, c4.y, acc[r]);
      acc[r] = fmaf(uv2.y, s4.y, acc[r]);
      acc[r] = fmaf(uv3.x, c4.x, acc[r]);
      acc[r] = fmaf(uv3.y, s4.x, acc[r]);
    }
  }
#pragma unroll
  for (int r = 0; r < 16; ++r)
    Y[(size_t)ch*NIMG + (h0 + r)*192 + w] = acc[r];
}

// ---------------- K4: per-pixel channel normalization -> bf16 (h,w,c) ---------
__global__ __launch_bounds__(192) void k_norm(const float* __restrict__ Y,
                                              ushort* __restrict__ SNh,
                                              ushort* __restrict__ TNh){
  int h = blockIdx.x, w = threadIdx.x;
  int which = blockIdx.y;                // 0 = src, 1 = tgt
  int pix = h*192 + w;
  const float* base = Y + (size_t)which*64*NIMG + pix;
  float x[64];
  float ss = 0.0f;
#pragma unroll
  for (int c = 0; c < 64; ++c){
    x[c] = base[(size_t)c*NIMG];
    ss = fmaf(x[c], x[c], ss);
  }
  float rn = 1.0f / sqrtf(ss);
  ushort* o = (which ? TNh : SNh) + (size_t)pix*64;
#pragma unroll
  for (int q = 0; q < 8; ++q){
    ushort tmp[8];
#pragma unroll
    for (int e = 0; e < 8; ++e) tmp[e] = bf16rtn(x[q*8 + e] * rn);
    *reinterpret_cast<uint4*>(o + q*8) = *reinterpret_cast<const uint4*>(tmp);
  }
}

// ---------------- K5: fused corr + softmax + outputs, bf16 LDS e-cache --------
// Block = (h, 16-w tile), 4 waves, ~39KB LDS -> 4 blocks/CU.  |logit| <= temp
// (unit vectors) => fixed offset exp(s-temp), no max pass.
__global__ __launch_bounds__(256, 4) void k_corrsm(const ushort* __restrict__ SNh,
                                                   const ushort* __restrict__ TNh,
                                                   const int* __restrict__ temp,
                                                   const float* __restrict__ frames,
                                                   float* __restrict__ dout){
  __shared__ ushort eLu[16*ELS];         // bf16 e-cache, row stride 962
  __shared__ float red7[7][16][16];
  __shared__ float rsw[16];
  int h  = blockIdx.x;
  int bx = blockIdx.y;                   // w-tile 0..11
  int t  = threadIdx.x;
  int lane = t & 63, wv = t >> 6;
  int n = lane & 15, g = lane >> 4;
  int w0 = bx * 16;
  float tempf = (float)(*temp);

  const ushort* ap = TNh + ((size_t)(h*192 + w0 + n))*64 + g*8;
  short8v a0 = *reinterpret_cast<const short8v*>(ap);
  short8v a1 = *reinterpret_cast<const short8v*>(ap + 32);

  // ---- fill pass: waves split k ----
  for (int k = wv; k < KS; k += 4){
    int sh = h + k - 15; sh = sh < 0 ? 0 : (sh > 127 ? 127 : sh);
    const ushort* srow = SNh + (size_t)sh*192*64;
#pragma unroll
    for (int dj = 0; dj < 3; ++dj){
      int j0 = bx - 1 + dj;
      if (j0 < 0 || j0 > 11) continue;
      const ushort* bp = srow + ((size_t)(j0*16 + n))*64 + g*8;
      short8v b0 = *reinterpret_cast<const short8v*>(bp);
      short8v b1 = *reinterpret_cast<const short8v*>(bp + 32);
      f32x4 acc = {0.0f, 0.0f, 0.0f, 0.0f};
      acc = __builtin_amdgcn_mfma_f32_16x16x32_bf16(a0, b0, acc, 0, 0, 0);
      acc = __builtin_amdgcn_mfma_f32_16x16x32_bf16(a1, b1, acc, 0, 0, 0);
      int sx = j0*16 + n;
#pragma unroll
      for (int r = 0; r < 4; ++r){
        int wl = g*4 + r;
        int wg = w0 + wl;
        int l = sx - wg + 15;
        float e = __expf(acc[r]*tempf - tempf);
        ushort eb = bf16rtn(e);
        if (l >= 0 && l <= 30) eLu[wl*ELS + k*31 + l] = eb;
        if (bx == 0 && j0 == 0 && n == 0){          // left edge -> col 0
          for (int l2 = 0; l2 < 15 - wg; ++l2) eLu[wl*ELS + k*31 + l2] = eb;
        }
        if (bx == 11 && j0 == 11 && n == 15){       // right edge -> col 191
          for (int l2 = 207 - wg; l2 <= 30; ++l2) eLu[wl*ELS + k*31 + l2] = eb;
        }
      }
    }
  }
  __syncthreads();

  // ---- reduction pass: thread t -> w = t&15, k in {t>>4, t>>4+16} ----
  {
    float s=0, o0=0, o1=0, o2=0, p0=0, p1=0, en=0;
    int wl = t & 15;
    int wg = w0 + wl;
    for (int kk = t >> 4; kk < KS; kk += 16){
      int sh = h + kk - 15; sh = sh < 0 ? 0 : (sh > 127 ? 127 : sh);
      float dy = (float)(kk - 15);
      float dy2 = dy*dy;
      const float* f0p = frames + sh*192;
      const float* f1p = f0p + NPIX;
      const float* f2p = f0p + 2*NPIX;
      const ushort* src = eLu + wl*ELS + kk*31;
#pragma unroll
      for (int l = 0; l < KS; ++l){
        float e = bf2f(src[l]);
        float dx = (float)(l - 15);
        int ww = wg + l - 15; ww = ww < 0 ? 0 : (ww > 191 ? 191 : ww);
        s  += e;
        p0 = fmaf(e, dx, p0);
        p1 = fmaf(e, dy, p1);
        en = fmaf(e, sqrtf(dx*dx + dy2), en);
        o0 = fmaf(e, f0p[ww], o0);
        o1 = fmaf(e, f1p[ww], o1);
        o2 = fmaf(e, f2p[ww], o2);
      }
    }
    int q = t >> 4;
    red7[0][q][wl]=s;  red7[1][q][wl]=o0; red7[2][q][wl]=o1; red7[3][q][wl]=o2;
    red7[4][q][wl]=p0; red7[5][q][wl]=p1; red7[6][q][wl]=en;
  }
  __syncthreads();

  if (t < 16){
    float a[7];
#pragma unroll
    for (int j = 0; j < 7; ++j){
      float acc = 0.0f;
#pragma unroll
      for (int qq = 0; qq < 16; ++qq) acc += red7[j][qq][t];
      a[j] = acc;
    }
    float rs = 1.0f / a[0];
    int pix = h*192 + w0 + t;
    dout[0*NPIX + pix] = a[1]*rs;
    dout[1*NPIX + pix] = a[2]*rs;
    dout[2*NPIX + pix] = a[3]*rs;
    dout[OFF_POS + pix*2 + 0] = a[4]*rs;
    dout[OFF_POS + pix*2 + 1] = a[5]*rs;
    dout[OFF_EN + pix] = a[6]*rs;
    rsw[t] = rs;
  }
  __syncthreads();

  // ---- write pass: wave wv -> rows 4wv..4wv+3; 64 lanes = 256B contiguous ----
#pragma unroll
  for (int rr = 0; rr < 4; ++rr){
    int row = wv*4 + rr;
    float rsv = rsw[row];
    float* dst = dout + OFF_WGT + ((size_t)(h*192 + w0 + row))*NKL;
    const ushort* src = eLu + row*ELS;
#pragma unroll
    for (int i = 0; i < 15; ++i){
      int j = i*64 + lane;
      dst[j] = bf2f(src[j]) * rsv;
    }
    if (lane == 0) dst[960] = bf2f(src[960]) * rsv;
  }
}

extern "C" void kernel_launch(void* const* d_in, const int* in_sizes, int n_in,
                              void* d_out, int out_size, void* d_ws, size_t ws_size,
                              hipStream_t stream) {
  const float* frames = (const float*)d_in[0];   // (1,1,3,128,192)
  const float* feats  = (const float*)d_in[2];   // (1,2,64,128,192)
  const int*   temp   = (const int*)d_in[3];
  float* ws   = (float*)d_ws;
  float* dout = (float*)d_out;
  (void)in_sizes; (void)n_in; (void)out_size; (void)ws_size;

  float2* UV2 = (float2*)(ws + WS_U);
  float*  Y   = ws + WS_Y;
  ushort* SNh = (ushort*)(ws + WS_SN);
  ushort* TNh = (ushort*)(ws + WS_TN);

  hipLaunchKernelGGL(k_tables,  dim3(3),        dim3(256), 0, stream, ws);
  hipLaunchKernelGGL(k_colpass, dim3(1024),     dim3(192), 0, stream, feats, ws, UV2);
  hipLaunchKernelGGL(k_rowpass, dim3(1024),     dim3(192), 0, stream, UV2, ws, Y);
  hipLaunchKernelGGL(k_norm,    dim3(128, 2),   dim3(192), 0, stream, Y, SNh, TNh);
  hipLaunchKernelGGL(k_corrsm,  dim3(128, 12),  dim3(256), 0, stream, SNh, TNh, temp, frames, dout);
}